// Round 3
// baseline (487.245 us; speedup 1.0000x reference)
//
#include <hip/hip_runtime.h>
#include <math.h>

// Problem constants (fixed by setup_inputs)
#define M_TOK 16384   // B*T
#define DIM   256     // D (physical K of each split matrix)
#define VOC   8192    // V (=N)

// GEMM tiling: 256x256 tile, 8 waves, K-concat virtual GEMM K=768 (hh|lh|hl),
// BK=32, ring of 4 LDS K-tile buffers, prefetch distance 2, counted vmcnt(4).
#define BM 256
#define BN 256
#define BK 32
#define KT_TOT 24            // 768 / 32
#define NBLK_N (VOC / BN)    // 32
#define GAP_EPS 0.01f        // rescue trigger; split-bf16 d2 err ~1e-4 << 0.01

typedef unsigned short u16;
typedef unsigned long long u64;
typedef __attribute__((ext_vector_type(8))) __bf16 bf16x8;
typedef __attribute__((ext_vector_type(4))) float f32x4;

// ---- workspace layout (float-element offsets) ------------------------------
#define WS_ESQ      0                     // [8192]
#define WS_FLAGROWS 24576                 // [16384] int
#define WS_CANDV    40960                 // [<=64][16384] f32 (32 used)
#define WS_CANDI    1089536               // [<=64][16384] int
#define WS_CANDS    2138112               // [<=64][16384] f32
#define WS_XHI      3186688               // [16384*256] bf16 (2097152 f32 slots)
#define WS_XLO      5283840
#define WS_EHI      7380992               // [8192*256] bf16 (1048576 slots)
#define WS_ELO      8429568
#define WS_COUNTS   9478144               // [8192]
#define WS_SUMS     9486336               // [8192*256]
#define WS_FLAGCNT  11583488              // [16] int
// rescueBuf [16384] u64 aliases Xhi (dead after mfma_argmin; reduce writes it)
#define WS_RESCUE   WS_XHI
#define WS_ZERO_OFF_BYTES ((size_t)WS_COUNTS * 4)
#define WS_ZERO_BYTES     ((size_t)(8192 + 2097152 + 16) * 4)

// ---- out layout (float-element offsets): quantize, codes, new_embed, new_cs, new_ea
#define OUT_Q   0
#define OUT_C   4194304
#define OUT_NE  4210688
#define OUT_NCS 6307840
#define OUT_NEA 6316032

__device__ inline u16 f2bf_rn(float x) {
    unsigned u = __float_as_uint(x);
    unsigned r = u + 0x7FFFu + ((u >> 16) & 1u);   // round-to-nearest-even
    return (u16)(r >> 16);
}
__device__ inline float bf2f(u16 u) { return __uint_as_float(((unsigned)u) << 16); }
__device__ inline unsigned f2key(float f) {          // order-preserving uint
    unsigned b = __float_as_uint(f);
    return (b & 0x80000000u) ? ~b : (b | 0x80000000u);
}

// ---------------------------------------------------------------------------
// prep: split X,E into bf16 hi/lo; compute esq from fp32 originals.
__global__ __launch_bounds__(256) void prep_kernel(
    const float* __restrict__ X, const float* __restrict__ E,
    u16* __restrict__ Xhi, u16* __restrict__ Xlo,
    u16* __restrict__ Ehi, u16* __restrict__ Elo,
    float* __restrict__ esq)
{
    int row  = blockIdx.x * 4 + (threadIdx.x >> 6);
    int lane = threadIdx.x & 63;
    bool isX = row < M_TOK;
    int r = isX ? row : row - M_TOK;
    const float* src = isX ? X + (size_t)row * DIM : E + (size_t)r * DIM;
    float4 v = ((const float4*)src)[lane];

    ushort4 h, lo;
    {
        u16 hb = f2bf_rn(v.x); h.x = hb; lo.x = f2bf_rn(v.x - bf2f(hb));
        hb = f2bf_rn(v.y); h.y = hb; lo.y = f2bf_rn(v.y - bf2f(hb));
        hb = f2bf_rn(v.z); h.z = hb; lo.z = f2bf_rn(v.z - bf2f(hb));
        hb = f2bf_rn(v.w); h.w = hb; lo.w = f2bf_rn(v.w - bf2f(hb));
    }
    u16* dh = isX ? Xhi : Ehi;
    u16* dl = isX ? Xlo : Elo;
    *(ushort4*)&dh[(size_t)r * DIM + lane * 4] = h;
    *(ushort4*)&dl[(size_t)r * DIM + lane * 4] = lo;

    if (!isX) {
        float s = v.x * v.x + v.y * v.y + v.z * v.z + v.w * v.w;
        #pragma unroll
        for (int o = 1; o < 64; o <<= 1) s += __shfl_xor(s, o, 64);
        if (lane == 0) esq[r] = s;
    }
}

// ---------------------------------------------------------------------------
// mfma_argmin via K-concat virtual GEMM: C = A'.B'^T, A'=[Xhi|Xlo|Xhi],
// B'=[Ehi|Ehi|Elo], K=768 -> dot = hh + lh + hl. 24 K-tiles of BK=32.
// Per K-tile t: buffer t&3 (4x32KB ring), staging of tile t+2 spread across
// the 2 phases (2x 8KB global_load_lds sweeps each), gate = vmcnt(4) at tile
// end (counted, never 0 in main loop: the 4 in-flight are tile t+2's).
// Phase = {ds_read frags | gll prefetch | s_barrier | lgkmcnt(0) |
// setprio(1) 16 MFMA setprio(0)} x2, second phase ends with gate + barrier.
// LDS rows are 64B with the R0-proven XOR chunk swizzle (0 bank conflicts).
#define GLL(SRC, DST) __builtin_amdgcn_global_load_lds( \
    (const __attribute__((address_space(1))) unsigned int*)(SRC), \
    (__attribute__((address_space(3))) unsigned int*)(DST), 16, 0, 0)
#define VMCNT(n) asm volatile("s_waitcnt vmcnt(" #n ")" ::: "memory")
#define LGKM0    asm volatile("s_waitcnt lgkmcnt(0)" ::: "memory")
#define SCHEDB   __builtin_amdgcn_sched_barrier(0)

__global__ __launch_bounds__(512, 2) void mfma_argmin_kernel(
    const u16* __restrict__ Xhi, const u16* __restrict__ Xlo,
    const u16* __restrict__ Ehi, const u16* __restrict__ Elo,
    const float* __restrict__ esq,
    float* __restrict__ candV, int* __restrict__ candI, float* __restrict__ candS)
{
    __shared__ __align__(16) char lds[131072];   // 4 x (A 16KB | B 16KB)

    const int tid = threadIdx.x;
    const int l = tid & 63, w = tid >> 6;
    const int wm = w >> 2, wn = w & 3;           // wave grid 2(M) x 4(N)
    const int m0 = blockIdx.x * BM, n0 = blockIdx.y * BN;

    f32x4 acc[8][4];
    #pragma unroll
    for (int i = 0; i < 8; ++i)
        #pragma unroll
        for (int j = 0; j < 4; ++j) acc[i][j] = (f32x4)0.0f;

    // staging geometry: sweep = 512 thr x 16B = 8KB = 128 rows x 64B.
    // stored[row][slot] = global[row][slot ^ ((row>>1)&3)] (R0-proven pair)
    const int srow   = tid >> 2;                         // 0..127
    const int schunk = (tid & 3) ^ ((tid >> 3) & 3);     // pre-swizzled source

    // fragment geometry (16x16x32): lane = fq*16 + frow
    const int frow = l & 15, fq = l >> 4;
    const int fs = (fq ^ ((frow >> 1) & 3)) * 16;
    const int aRowOff = (wm * 128 + frow) * 64 + fs;            // + mt*1024
    const int bRowOff = 16384 + (wn * 64 + frow) * 64 + fs;     // + nt*1024

    // K-tile t: seg = t>>3 (0:hh 1:lh 2:hl), k0 = (t&7)*32 elements
#define STAGE_A(TT) { \
    const u16* _b = ((((TT) >> 3) == 1) ? Xlo : Xhi); \
    const u16* _s = _b + (size_t)(m0 + srow) * DIM + (((TT) & 7) * 32) + schunk * 8; \
    char* _d = lds + ((((TT) & 3)) * 32768) + tid * 16; \
    GLL(_s, _d); GLL(_s + 128 * DIM, _d + 8192); }
#define STAGE_B(TT) { \
    const u16* _b = ((((TT) >> 3) == 2) ? Elo : Ehi); \
    const u16* _s = _b + (size_t)(n0 + srow) * DIM + (((TT) & 7) * 32) + schunk * 8; \
    char* _d = lds + ((((TT) & 3)) * 32768) + 16384 + tid * 16; \
    GLL(_s, _d); GLL(_s + 128 * DIM, _d + 8192); }

#define KTILE_BODY(T, DO_STAGE, GATE_STMT) { \
    const char* bb = lds + (((T) & 3) * 32768); \
    bf16x8 bfr[4], afr[4]; \
    _Pragma("unroll") for (int nt = 0; nt < 4; ++nt) \
        bfr[nt] = *(const bf16x8*)(bb + bRowOff + nt * 1024); \
    _Pragma("unroll") for (int mt = 0; mt < 4; ++mt) \
        afr[mt] = *(const bf16x8*)(bb + aRowOff + mt * 1024); \
    if (DO_STAGE) STAGE_A((T) + 2); \
    __builtin_amdgcn_s_barrier(); \
    LGKM0; SCHEDB; \
    __builtin_amdgcn_s_setprio(1); \
    _Pragma("unroll") for (int nt = 0; nt < 4; ++nt) \
        _Pragma("unroll") for (int mt = 0; mt < 4; ++mt) \
            acc[mt][nt] = __builtin_amdgcn_mfma_f32_16x16x32_bf16(afr[mt], bfr[nt], acc[mt][nt], 0, 0, 0); \
    __builtin_amdgcn_s_setprio(0); \
    __builtin_amdgcn_s_barrier(); \
    _Pragma("unroll") for (int mt = 0; mt < 4; ++mt) \
        afr[mt] = *(const bf16x8*)(bb + aRowOff + (mt + 4) * 1024); \
    if (DO_STAGE) STAGE_B((T) + 2); \
    __builtin_amdgcn_s_barrier(); \
    LGKM0; SCHEDB; \
    __builtin_amdgcn_s_setprio(1); \
    _Pragma("unroll") for (int nt = 0; nt < 4; ++nt) \
        _Pragma("unroll") for (int mt = 0; mt < 4; ++mt) \
            acc[mt + 4][nt] = __builtin_amdgcn_mfma_f32_16x16x32_bf16(afr[mt], bfr[nt], acc[mt + 4][nt], 0, 0, 0); \
    __builtin_amdgcn_s_setprio(0); \
    GATE_STMT; SCHEDB; \
    __builtin_amdgcn_s_barrier(); }

    // prologue: stage tiles 0,1 (issue order: t0.A t0.B t1.A t1.B);
    // vmcnt(4) -> tile 0's 4 sweeps landed, tile 1's may fly.
    STAGE_A(0); STAGE_B(0); STAGE_A(1); STAGE_B(1);
    VMCNT(4); SCHEDB;
    __builtin_amdgcn_s_barrier();

    // main loop: tile t computes from buf t&3, stages t+2 into buf (t+2)&3.
    // End-of-t ledger: outstanding = t+1's 4 + t+2's 4 -> vmcnt(4) lands t+1.
    // Buf-write hazard: writes to (t+2)&3 = (t-2)&3 start >=2 barriers after
    // all reads of tile t-2 ended. Per-wave gate precedes barrier -> all
    // waves' sweeps visible after barrier.
    #pragma unroll 1
    for (int t = 0; t < KT_TOT - 2; ++t) {
        KTILE_BODY(t, true, VMCNT(4));
    }
    // tail: no staging; t=22 gate drains tile 23 (last in flight), t=23 none.
    KTILE_BODY(KT_TOT - 2, false, VMCNT(0));
    KTILE_BODY(KT_TOT - 1, false, (void)0);

    // ---- epilogue: per-row top-2 argmin of val = esq[n] - 2*dot
    __syncthreads();                     // tiles dead; reuse LDS for reduce
    float* smB = (float*)lds;            // [4][256]
    int*   smI = (int*)(lds + 4096);
    float* smS = (float*)(lds + 8192);

    float eq[4];
    #pragma unroll
    for (int nt = 0; nt < 4; ++nt) eq[nt] = esq[n0 + wn * 64 + nt * 16 + frow];

    #pragma unroll
    for (int mt = 0; mt < 8; ++mt) {
        #pragma unroll
        for (int r = 0; r < 4; ++r) {
            float b = 3.4e38f, s = 3.4e38f;
            int bi = 0;
            #pragma unroll
            for (int nt = 0; nt < 4; ++nt) {
                float v = fmaf(-2.0f, acc[mt][nt][r], eq[nt]);
                int col = n0 + wn * 64 + nt * 16 + frow;
                if (v < b) { s = b; b = v; bi = col; }
                else if (v < s) s = v;
            }
            #pragma unroll
            for (int o = 1; o < 16; o <<= 1) {
                float ob = __shfl_xor(b, o, 64);
                int   oi = __shfl_xor(bi, o, 64);
                float os = __shfl_xor(s, o, 64);
                bool take = (ob < b) || (ob == b && oi < bi);
                float keep = take ? b : ob;
                b  = take ? ob : b;
                bi = take ? oi : bi;
                s  = fminf(fminf(s, os), keep);
            }
            if (frow == 0) {
                int m_loc = wm * 128 + mt * 16 + fq * 4 + r;
                smB[wn * 256 + m_loc] = b;
                smI[wn * 256 + m_loc] = bi;
                smS[wn * 256 + m_loc] = s;
            }
        }
    }
    __syncthreads();
    if (tid < 256) {
        float b = smB[tid]; int bi = smI[tid]; float s = smS[tid];
        #pragma unroll
        for (int q = 1; q < 4; ++q) {
            float ob = smB[q * 256 + tid];
            int   oi = smI[q * 256 + tid];
            float os = smS[q * 256 + tid];
            bool take = ob < b;                // tie -> lower wn = lower cols
            float keep = take ? b : ob;
            b = take ? ob : b;
            bi = take ? oi : bi;
            s = fminf(fminf(s, os), keep);
        }
        size_t e = (size_t)blockIdx.y * M_TOK + (m0 + tid);
        candV[e] = b; candI[e] = bi; candS[e] = s;
    }
}

// ---------------------------------------------------------------------------
// reduce: fold 32 n-block candidates per row. Batched-8 independent candV
// loads; candS/candI read lazily only for the winning block (true global
// second = min(2nd-min over candV, candS[e*])). Packs (key|idx) u64 into
// rescueBuf; flagged rows get ~0 sentinel for rescue's atomicMin.
__global__ __launch_bounds__(64) void reduce_kernel(
    const float* __restrict__ candV, const int* __restrict__ candI,
    const float* __restrict__ candS,
    int* __restrict__ flagCnt, int* __restrict__ flagRows,
    u64* __restrict__ rescueBuf)
{
    int row = blockIdx.x * 64 + threadIdx.x;
    float best = 3.4e38f, second = 3.4e38f;
    int ebest = 0;
    #pragma unroll
    for (int e0 = 0; e0 < NBLK_N; e0 += 8) {
        float v[8];
        #pragma unroll
        for (int j = 0; j < 8; ++j) v[j] = candV[(size_t)(e0 + j) * M_TOK + row];
        #pragma unroll
        for (int j = 0; j < 8; ++j) {
            if (v[j] < best) { second = best; best = v[j]; ebest = e0 + j; }
            else second = fminf(second, v[j]);
        }
    }
    int bi = candI[(size_t)ebest * M_TOK + row];
    second = fminf(second, candS[(size_t)ebest * M_TOK + row]);
    u64 pk = ((u64)f2key(best) << 32) | (unsigned)bi;
    if (second - best < GAP_EPS) {
        pk = ~0ull;
        int k = atomicAdd(flagCnt, 1);
        flagRows[k] = row;
    }
    rescueBuf[row] = pk;
}

// ---------------------------------------------------------------------------
// rescue: exact fp32 argmin for flagged rows. BATCHED: each work item is
// (group of 8 flagged rows, 256-code chunk). xr[8][256] staged in LDS; the
// inner fma reads xr with wave-uniform addresses (broadcast). Winner via
// per-wave u64 shuffle-min then one atomicMin per (wave,row).
__global__ __launch_bounds__(256) void rescue_kernel(
    const float* __restrict__ X, const float* __restrict__ E,
    const float* __restrict__ esq,
    const int* __restrict__ flagCnt, const int* __restrict__ flagRows,
    u64* __restrict__ rescueBuf)
{
    __shared__ float xr[8][DIM];
    __shared__ int rowids[8];
    const int nflag = flagCnt[0];
    const int ngroups = (nflag + 7) >> 3;
    const int nwork = ngroups * 32;
    const int lane = threadIdx.x & 63;

    for (int wk = blockIdx.x; wk < nwork; wk += gridDim.x) {
        const int g = wk >> 5, chunk = wk & 31;
        __syncthreads();                       // protect xr/rowids reuse
        if (threadIdx.x < 8) {
            int idx = g * 8 + threadIdx.x;
            rowids[threadIdx.x] = (idx < nflag) ? flagRows[idx] : -1;
        }
        {
            int i = threadIdx.x >> 5;          // row slot 0..7
            int idx = g * 8 + i;
            int row = flagRows[(idx < nflag) ? idx : (nflag - 1)];
            const float4* src = (const float4*)(X + (size_t)row * DIM);
            int c4 = (threadIdx.x & 31) * 2;
            ((float4*)xr[i])[c4]     = src[c4];
            ((float4*)xr[i])[c4 + 1] = src[c4 + 1];
        }
        __syncthreads();

        const int c = (chunk << 8) + threadIdx.x;
        const float4* er = (const float4*)(E + (size_t)c * DIM);
        float dot[8];
        #pragma unroll
        for (int i = 0; i < 8; ++i) dot[i] = 0.0f;
        #pragma unroll 4
        for (int k = 0; k < DIM / 4; ++k) {
            float4 e4 = er[k];
            #pragma unroll
            for (int i = 0; i < 8; ++i) {
                float4 x4 = ((const float4*)xr[i])[k];   // wave-uniform: broadcast
                dot[i] = fmaf(x4.x, e4.x, dot[i]);
                dot[i] = fmaf(x4.y, e4.y, dot[i]);
                dot[i] = fmaf(x4.z, e4.z, dot[i]);
                dot[i] = fmaf(x4.w, e4.w, dot[i]);
            }
        }
        float eq = esq[c];
        #pragma unroll
        for (int i = 0; i < 8; ++i) {
            float v = fmaf(-2.0f, dot[i], eq);
            u64 pk = ((u64)f2key(v) << 32) | (unsigned)c;
            #pragma unroll
            for (int o = 1; o < 64; o <<= 1) {
                u64 other = __shfl_xor(pk, o, 64);
                pk = (other < pk) ? other : pk;
            }
            if (lane == 0 && g * 8 + i < nflag)
                atomicMin(&rescueBuf[rowids[i]], pk);
        }
    }
}

// ---------------------------------------------------------------------------
// assign: unpack code, write codes + quantize (STE), scatter counts/sums.
__global__ __launch_bounds__(256) void assign_kernel(
    const float* __restrict__ X, const float* __restrict__ E,
    const u64* __restrict__ rescueBuf,
    float* __restrict__ out_q, float* __restrict__ out_codes,
    float* __restrict__ counts, float* __restrict__ sums)
{
    int t = blockIdx.x * 4 + (threadIdx.x >> 6);
    int lane = threadIdx.x & 63;
    int code = (int)(unsigned)(rescueBuf[t] & 0xFFFFFFFFull);
    if (lane == 0) {
        out_codes[t] = (float)code;
        atomicAdd(&counts[code], 1.0f);
    }
    float4 x = *(const float4*)&X[(size_t)t * DIM + lane * 4];
    float4 e = *(const float4*)&E[(size_t)code * DIM + lane * 4];
    float4 q;
    q.x = x.x + (e.x - x.x);
    q.y = x.y + (e.y - x.y);
    q.z = x.z + (e.z - x.z);
    q.w = x.w + (e.w - x.w);
    *(float4*)&out_q[(size_t)t * DIM + lane * 4] = q;
    float* s = &sums[(size_t)code * DIM + lane * 4];
    atomicAdd(s + 0, x.x);
    atomicAdd(s + 1, x.y);
    atomicAdd(s + 2, x.z);
    atomicAdd(s + 3, x.w);
}

// ---------------------------------------------------------------------------
__global__ __launch_bounds__(256) void finalize_kernel(
    const float* __restrict__ cs, const float* __restrict__ ea,
    const float* __restrict__ counts, const float* __restrict__ sums,
    float* __restrict__ out_embed, float* __restrict__ out_cs,
    float* __restrict__ out_ea)
{
    int vd = blockIdx.x * 256 + threadIdx.x;
    int v = vd >> 8, d = vd & 255;
    float cnt = counts[v];
    float ncs = cs[v] * 0.99f + cnt * 0.01f;
    float cb  = sums[vd] * (1.0f / 2048.0f);
    float nea = ea[vd] * 0.99f + cb * 0.01f;
    out_ea[vd] = nea;
    out_embed[vd] = nea / (ncs + 1e-5f);
    if (d == 0) out_cs[v] = ncs;
}

// ---------------------------------------------------------------------------
extern "C" void kernel_launch(void* const* d_in, const int* in_sizes, int n_in,
                              void* d_out, int out_size, void* d_ws, size_t ws_size,
                              hipStream_t stream)
{
    const float* input     = (const float*)d_in[0];
    const float* embed     = (const float*)d_in[1];
    const float* cluster   = (const float*)d_in[2];
    const float* embed_avg = (const float*)d_in[3];

    float* out = (float*)d_out;
    float* ws  = (float*)d_ws;

    float* esq      = ws + WS_ESQ;
    int*   flagRows = (int*)(ws + WS_FLAGROWS);
    float* candV    = ws + WS_CANDV;
    int*   candI    = (int*)(ws + WS_CANDI);
    float* candS    = ws + WS_CANDS;
    u16*   Xhi      = (u16*)(ws + WS_XHI);
    u16*   Xlo      = (u16*)(ws + WS_XLO);
    u16*   Ehi      = (u16*)(ws + WS_EHI);
    u16*   Elo      = (u16*)(ws + WS_ELO);
    float* counts   = ws + WS_COUNTS;
    float* sums     = ws + WS_SUMS;
    int*   flagCnt  = (int*)(ws + WS_FLAGCNT);
    u64*   rescueBuf= (u64*)(ws + WS_RESCUE);   // aliases dead Xhi

    hipMemsetAsync((char*)d_ws + WS_ZERO_OFF_BYTES, 0, WS_ZERO_BYTES, stream);

    prep_kernel<<<(M_TOK + VOC) / 4, 256, 0, stream>>>(
        input, embed, Xhi, Xlo, Ehi, Elo, esq);

    dim3 g1(M_TOK / BM, VOC / BN);   // 64 x 32
    mfma_argmin_kernel<<<g1, 512, 0, stream>>>(
        Xhi, Xlo, Ehi, Elo, esq, candV, candI, candS);

    reduce_kernel<<<M_TOK / 64, 64, 0, stream>>>(
        candV, candI, candS, flagCnt, flagRows, rescueBuf);

    rescue_kernel<<<1024, 256, 0, stream>>>(
        input, embed, esq, flagCnt, flagRows, rescueBuf);

    assign_kernel<<<M_TOK / 4, 256, 0, stream>>>(
        input, embed, rescueBuf, out + OUT_Q, out + OUT_C, counts, sums);

    finalize_kernel<<<(VOC * DIM) / 256, 256, 0, stream>>>(
        cluster, embed_avg, counts, sums,
        out + OUT_NE, out + OUT_NCS, out + OUT_NEA);
}